// Round 3
// baseline (222.035 us; speedup 1.0000x reference)
//
#include <hip/hip_runtime.h>
#include <math.h>

#define NS 1024   // speakers
#define NU 64     // utterances per speaker
#define NE 256    // embedding dim

typedef __attribute__((ext_vector_type(8))) short short8;
typedef __attribute__((ext_vector_type(4))) float f32x4;
typedef __attribute__((ext_vector_type(4))) unsigned short us4;

// round-to-nearest-even fp32 -> bf16 bits
__device__ static inline unsigned short f2bf(float f) {
  unsigned int u = __float_as_uint(f);
  unsigned int r = (u + 0x7fffu + ((u >> 16) & 1u)) >> 16;
  return (unsigned short)r;
}

__device__ static inline void gld_lds16(const void* g, void* l) {
  __builtin_amdgcn_global_load_lds(
      (const __attribute__((address_space(1))) unsigned int*)g,
      (__attribute__((address_space(3))) unsigned int*)l, 16, 0, 0);
}

// Cb layout (bf16, MFMA-B-fragment-permuted), same as round 2:
// global 1KB block G = (n>>4)*8 + (k>>5); within block,
//   idx(n,k) = G*512 + (((k>>3)&3)*16 + (n&15))*8 + (k&7)   (ushort units)
// Chunk ch (64 cols) = blocks [ch*32, ch*32+32) -> contiguous 32 KB.

__global__ __launch_bounds__(256) void centroid_kernel(
    const float* __restrict__ embeds, unsigned short* __restrict__ Cb,
    float* __restrict__ normsum, float* __restrict__ out) {
  int k = blockIdx.x;   // speaker
  int t = threadIdx.x;
  int wave = t >> 6, e4 = t & 63;  // e4: float4 group (4 consecutive elems)
  // each wave sums 16 of the 64 utterances, float4-vectorized
  const float4* base =
      (const float4*)(embeds + (size_t)k * NU * NE) + wave * 16 * 64 + e4;
  float4 s = {0.f, 0.f, 0.f, 0.f};
#pragma unroll
  for (int i = 0; i < 16; ++i) {
    float4 v = base[i * 64];
    s.x += v.x; s.y += v.y; s.z += v.z; s.w += v.w;
  }
  __shared__ float4 ps[4][64];
  ps[wave][e4] = s;
  __syncthreads();
  if (t < 64) {
    float4 a = ps[0][t], b = ps[1][t], c = ps[2][t], d = ps[3][t];
    float4 s4;
    s4.x = a.x + b.x + c.x + d.x;
    s4.y = a.y + b.y + c.y + d.y;
    s4.z = a.z + b.z + c.z + d.z;
    s4.w = a.w + b.w + c.w + d.w;
    float sq = s4.x * s4.x + s4.y * s4.y + s4.z * s4.z + s4.w * s4.w;
#pragma unroll
    for (int off = 32; off; off >>= 1) sq += __shfl_xor(sq, off, 64);
    float nrm = sqrtf(sq);
    float inv = 1.f / nrm;
    // permuted bf16 store; elements e = 4t..4t+3 are contiguous in Cb:
    int G = (k >> 4) * 8 + (t >> 3);
    int off = (((t >> 1) & 3) * 16 + (k & 15)) * 8 + (t & 1) * 4;
    us4 v;
    v[0] = f2bf(s4.x * inv);
    v[1] = f2bf(s4.y * inv);
    v[2] = f2bf(s4.z * inv);
    v[3] = f2bf(s4.w * inv);
    *(us4*)(Cb + (size_t)G * 512 + off) = v;
    if (t == 0) {
      normsum[k] = nrm;
      if (k == 0) { out[0] = 0.f; out[1] = 0.f; }  // replaces memset dispatch
    }
  }
}

__global__ __launch_bounds__(512, 4) void main_kernel(
    const float* __restrict__ embeds, const unsigned short* __restrict__ Cb,
    const float* __restrict__ normsum, const float* __restrict__ wp,
    const float* __restrict__ bp, float* __restrict__ out) {
  __shared__ __align__(16) unsigned short Bbuf[2][16384];  // 2 x 32 KB
  __shared__ float n2s[256];
  __shared__ float gtl[256];
  __shared__ float sE[256];
  __shared__ int aE[256];

  int t = threadIdx.x;
  int wave = t >> 6, lane = t & 63;
  int c = lane & 15, q = lane >> 4;
  int b0 = blockIdx.x;              // 0..255
  int jspk = b0 * 4 + (wave >> 1);  // this wave's speaker (diag column)
  int r0 = b0 * 256 + wave * 32;    // global row base for this wave

  float w = *wp, bia = *bp;
  const float L2E = 1.4426950408889634f;
  float M0 = fabsf(w) + bia;        // >= any logit (cosines in [-1,1])
  float wl = w * L2E;               // p = 2^(d*wl + cl) = exp(l - M0)
  float cl = (bia - M0) * L2E;
  float ns = normsum[jspk];

  // ---- issue chunk-0 staging first so L2 fetch overlaps A-load ----
  {
#pragma unroll
    for (int i = 0; i < 4; ++i) {
      int blk = i * 8 + wave;
      gld_lds16(Cb + blk * 512 + lane * 8, &Bbuf[0][blk * 512 + lane * 8]);
    }
  }

  // ---- load A fragments (32 rows x 256 K per wave) into registers ----
  // A-frag layout: lane holds A[m = lane&15][k = q*8 + j], per (mtile, kstep)
  short8 af[2][8];
  float n2p[2];
#pragma unroll
  for (int mt = 0; mt < 2; ++mt) {
    const float* rowp = embeds + (size_t)(r0 + mt * 16 + c) * NE;
    float acc2 = 0.f;
#pragma unroll
    for (int s = 0; s < 8; ++s) {
      int k0 = s * 32 + q * 8;
      float4 x = *(const float4*)(rowp + k0);
      float4 y = *(const float4*)(rowp + k0 + 4);
      acc2 += x.x * x.x + x.y * x.y + x.z * x.z + x.w * x.w;
      acc2 += y.x * y.x + y.y * y.y + y.z * y.z + y.w * y.w;
      short8 f;
      f[0] = (short)f2bf(x.x); f[1] = (short)f2bf(x.y);
      f[2] = (short)f2bf(x.z); f[3] = (short)f2bf(x.w);
      f[4] = (short)f2bf(y.x); f[5] = (short)f2bf(y.y);
      f[6] = (short)f2bf(y.z); f[7] = (short)f2bf(y.w);
      af[mt][s] = f;
    }
    n2p[mt] = acc2;
  }
#pragma unroll
  for (int mt = 0; mt < 2; ++mt) {
    n2p[mt] += __shfl_xor(n2p[mt], 16, 64);
    n2p[mt] += __shfl_xor(n2p[mt], 32, 64);
  }
  if (q == 0) {
    n2s[wave * 32 + c] = n2p[0];
    n2s[wave * 32 + 16 + c] = n2p[1];
  }

  // ---- per-lane softmax state (2 mtiles x 4 regs = 8 row-slots) ----
  float ssum[2][4];
  float pmax[2][4];
  int ai[2][4];
#pragma unroll
  for (int mt = 0; mt < 2; ++mt)
#pragma unroll
    for (int r = 0; r < 4; ++r) {
      ssum[mt][r] = 0.f;
      pmax[mt][r] = 0.f;   // p > 0 always
      ai[mt][r] = 0;
    }

  __syncthreads();  // chunk 0 staged; n2s published

  // ---- main loop over 16 N-chunks of 64 columns ----
  for (int ch = 0; ch < 16; ++ch) {
    const unsigned short* buf = Bbuf[ch & 1];
    if (ch + 1 < 16) {
      const unsigned short* src = Cb + (size_t)(ch + 1) * 16384;
      unsigned short* dst = Bbuf[(ch + 1) & 1];
#pragma unroll
      for (int i = 0; i < 4; ++i) {
        int blk = i * 8 + wave;
        gld_lds16(src + blk * 512 + lane * 8, dst + blk * 512 + lane * 8);
      }
    }

    for (int nt = 0; nt < 4; ++nt) {
      f32x4 acc0 = {0.f, 0.f, 0.f, 0.f};
      f32x4 acc1 = {0.f, 0.f, 0.f, 0.f};
#pragma unroll
      for (int s = 0; s < 8; ++s) {
        short8 bfrag = *(const short8*)(buf + ((nt * 8 + s) * 64 + lane) * 8);
        acc0 = __builtin_amdgcn_mfma_f32_16x16x32_bf16(af[0][s], bfrag, acc0,
                                                       0, 0, 0);
        acc1 = __builtin_amdgcn_mfma_f32_16x16x32_bf16(af[1][s], bfrag, acc1,
                                                       0, 0, 0);
      }
      float dv[2][4];
#pragma unroll
      for (int r = 0; r < 4; ++r) { dv[0][r] = acc0[r]; dv[1][r] = acc1[r]; }

      // diagonal fixup — wave-uniform guard, only 1 of 64 nt-steps enters
      if ((jspk >> 4) == ch * 4 + nt) {
        if (c == (jspk & 15)) {
#pragma unroll
          for (int mt = 0; mt < 2; ++mt)
#pragma unroll
            for (int r = 0; r < 4; ++r) {
              int rl = wave * 32 + mt * 16 + q * 4 + r;
              float d = dv[mt][r];
              float n2 = n2s[rl];
              float Sv = d * ns;
              float den = fmaxf(fmaf(ns, ns, n2) - 2.f * Sv, 1e-30f);
              float val = (Sv - n2) * __frsqrt_rn(den);
              gtl[rl] = fmaf(w, val, bia);
              dv[mt][r] = val;
            }
        }
      }

      int col = ch * 64 + nt * 16 + c;
#pragma unroll
      for (int mt = 0; mt < 2; ++mt)
#pragma unroll
        for (int r = 0; r < 4; ++r) {
          float p = exp2f(fmaf(dv[mt][r], wl, cl));  // exp(l - M0), monotone
          ssum[mt][r] += p;
          if (p > pmax[mt][r]) {
            pmax[mt][r] = p;
            ai[mt][r] = col;
          }
        }
    }
    __syncthreads();
  }

  // ---- cross-lane (16 column-lanes) reduction per row-slot ----
#pragma unroll
  for (int mt = 0; mt < 2; ++mt)
#pragma unroll
    for (int r = 0; r < 4; ++r) {
      float s = ssum[mt][r];
      s += __shfl_xor(s, 1, 64);
      s += __shfl_xor(s, 2, 64);
      s += __shfl_xor(s, 4, 64);
      s += __shfl_xor(s, 8, 64);
      float m = pmax[mt][r];
      int idx = ai[mt][r];
#pragma unroll
      for (int off = 1; off < 16; off <<= 1) {
        float m2 = __shfl_xor(m, off, 64);
        int i2 = __shfl_xor(idx, off, 64);
        if (m2 > m || (m2 == m && i2 < idx)) { m = m2; idx = i2; }
      }
      if (c == 0) {
        int rl = wave * 32 + mt * 16 + q * 4 + r;
        sE[rl] = s;
        aE[rl] = idx;
      }
    }
  __syncthreads();

  // ---- final per-row combine (256 rows on waves 0..3) ----
  if (t < 256) {
    int spk = b0 * 4 + (t >> 6);  // wave-uniform
    float lse = M0 + __logf(sE[t]);
    float lossr = lse - gtl[t];
    float corr = (aE[t] == spk) ? 1.f : 0.f;
#pragma unroll
    for (int off = 32; off; off >>= 1) {
      lossr += __shfl_xor(lossr, off, 64);
      corr += __shfl_xor(corr, off, 64);
    }
    if ((t & 63) == 0) {
      const float inv = 1.f / (float)(NS * NU);
      atomicAdd(&out[0], lossr * inv);
      atomicAdd(&out[1], corr * inv);
    }
  }
}

extern "C" void kernel_launch(void* const* d_in, const int* in_sizes, int n_in,
                              void* d_out, int out_size, void* d_ws,
                              size_t ws_size, hipStream_t stream) {
  const float* embeds = (const float*)d_in[0];
  const float* w = (const float*)d_in[1];
  const float* b = (const float*)d_in[2];
  float* out = (float*)d_out;
  unsigned short* Cb = (unsigned short*)d_ws;   // 1024*256 bf16
  float* normsum = (float*)(Cb + NS * NE);      // 1024 floats

  centroid_kernel<<<NS, 256, 0, stream>>>(embeds, Cb, normsum, out);
  main_kernel<<<NS * NU / 256, 512, 0, stream>>>(embeds, Cb, normsum, w, b,
                                                 out);
}

// Round 4
// 196.241 us; speedup vs baseline: 1.1314x; 1.1314x over previous
//
#include <hip/hip_runtime.h>
#include <math.h>

#define NS 1024   // speakers
#define NU 64     // utterances per speaker
#define NE 256    // embedding dim

typedef __attribute__((ext_vector_type(8))) short short8;
typedef __attribute__((ext_vector_type(4))) float f32x4;
typedef __attribute__((ext_vector_type(4))) unsigned short us4;

// round-to-nearest-even fp32 -> bf16 bits
__device__ static inline unsigned short f2bf(float f) {
  unsigned int u = __float_as_uint(f);
  unsigned int r = (u + 0x7fffu + ((u >> 16) & 1u)) >> 16;
  return (unsigned short)r;
}

__device__ static inline void gld_lds16(const void* g, void* l) {
  __builtin_amdgcn_global_load_lds(
      (const __attribute__((address_space(1))) unsigned int*)g,
      (__attribute__((address_space(3))) unsigned int*)l, 16, 0, 0);
}

// Cb layout (bf16, MFMA-B-fragment-permuted):
// global 1KB block G = (n>>4)*8 + (k>>5); within block,
//   idx(n,k) = G*512 + (((k>>3)&3)*16 + (n&15))*8 + (k&7)   (ushort units)
// Chunk ch (32 cols) = blocks [ch*16, ch*16+16) -> contiguous 16 KB.

__global__ __launch_bounds__(256) void centroid_kernel(
    const float* __restrict__ embeds, unsigned short* __restrict__ Cb,
    float* __restrict__ normsum, float* __restrict__ out) {
  int k = blockIdx.x;   // speaker
  int t = threadIdx.x;
  int wave = t >> 6, e4 = t & 63;  // e4: float4 group (4 consecutive elems)
  const float4* base =
      (const float4*)(embeds + (size_t)k * NU * NE) + wave * 16 * 64 + e4;
  float4 s = {0.f, 0.f, 0.f, 0.f};
#pragma unroll
  for (int i = 0; i < 16; ++i) {
    float4 v = base[i * 64];
    s.x += v.x; s.y += v.y; s.z += v.z; s.w += v.w;
  }
  __shared__ float4 ps[4][64];
  ps[wave][e4] = s;
  __syncthreads();
  if (t < 64) {
    float4 a = ps[0][t], b = ps[1][t], c = ps[2][t], d = ps[3][t];
    float4 s4;
    s4.x = a.x + b.x + c.x + d.x;
    s4.y = a.y + b.y + c.y + d.y;
    s4.z = a.z + b.z + c.z + d.z;
    s4.w = a.w + b.w + c.w + d.w;
    float sq = s4.x * s4.x + s4.y * s4.y + s4.z * s4.z + s4.w * s4.w;
#pragma unroll
    for (int off = 32; off; off >>= 1) sq += __shfl_xor(sq, off, 64);
    float nrm = sqrtf(sq);
    float inv = 1.f / nrm;
    int G = (k >> 4) * 8 + (t >> 3);
    int off = (((t >> 1) & 3) * 16 + (k & 15)) * 8 + (t & 1) * 4;
    us4 v;
    v[0] = f2bf(s4.x * inv);
    v[1] = f2bf(s4.y * inv);
    v[2] = f2bf(s4.z * inv);
    v[3] = f2bf(s4.w * inv);
    *(us4*)(Cb + (size_t)G * 512 + off) = v;
    if (t == 0) {
      normsum[k] = nrm;
      if (k == 0) { out[0] = 0.f; out[1] = 0.f; }
    }
  }
}

__global__ __launch_bounds__(256, 4) void main_kernel(
    const float* __restrict__ embeds, const unsigned short* __restrict__ Cb,
    const float* __restrict__ normsum, const float* __restrict__ wp,
    const float* __restrict__ bp, float* __restrict__ out) {
  __shared__ __align__(16) unsigned short Bbuf[2][8192];  // 2 x 16 KB
  __shared__ float n2s[128];
  __shared__ float gtl[128];
  __shared__ float sE[128];
  __shared__ int aE[128];

  int t = threadIdx.x;
  int wave = t >> 6, lane = t & 63;
  int c = lane & 15, q = lane >> 4;
  int b0 = blockIdx.x;              // 0..511
  int jspk = b0 * 2 + (wave >> 1);  // this wave's speaker (diag column)
  int r0 = b0 * 128 + wave * 32;    // global row base for this wave

  float w = *wp, bia = *bp;
  const float L2E = 1.4426950408889634f;
  float M0 = fabsf(w) + bia;        // >= any logit (cosines in [-1,1])
  float wl = w * L2E;               // p = 2^(d*wl + cl) = exp(l - M0)
  float cl = (bia - M0) * L2E;
  float ns = normsum[jspk];

  // ---- issue chunk-0 staging first so L2 fetch overlaps A-load ----
  {
#pragma unroll
    for (int i = 0; i < 4; ++i) {
      int blk = i * 4 + wave;
      gld_lds16(Cb + blk * 512 + lane * 8, &Bbuf[0][blk * 512 + lane * 8]);
    }
  }

  // ---- load A fragments (32 rows x 256 K per wave) into registers ----
  // A-frag layout: lane holds A[m = lane&15][k = q*8 + j], per (mtile, kstep)
  short8 af[2][8];
  float n2p[2];
#pragma unroll
  for (int mt = 0; mt < 2; ++mt) {
    const float* rowp = embeds + (size_t)(r0 + mt * 16 + c) * NE;
    float acc2 = 0.f;
#pragma unroll
    for (int s = 0; s < 8; ++s) {
      int k0 = s * 32 + q * 8;
      float4 x = *(const float4*)(rowp + k0);
      float4 y = *(const float4*)(rowp + k0 + 4);
      acc2 += x.x * x.x + x.y * x.y + x.z * x.z + x.w * x.w;
      acc2 += y.x * y.x + y.y * y.y + y.z * y.z + y.w * y.w;
      short8 f;
      f[0] = (short)f2bf(x.x); f[1] = (short)f2bf(x.y);
      f[2] = (short)f2bf(x.z); f[3] = (short)f2bf(x.w);
      f[4] = (short)f2bf(y.x); f[5] = (short)f2bf(y.y);
      f[6] = (short)f2bf(y.z); f[7] = (short)f2bf(y.w);
      af[mt][s] = f;
    }
    n2p[mt] = acc2;
  }
#pragma unroll
  for (int mt = 0; mt < 2; ++mt) {
    n2p[mt] += __shfl_xor(n2p[mt], 16, 64);
    n2p[mt] += __shfl_xor(n2p[mt], 32, 64);
  }
  if (q == 0) {
    n2s[wave * 32 + c] = n2p[0];
    n2s[wave * 32 + 16 + c] = n2p[1];
  }

  // ---- per-lane softmax state (2 mtiles x 4 regs = 8 row-slots) ----
  float ssum[2][4];
  float pmax[2][4];
  int ai[2][4];
#pragma unroll
  for (int mt = 0; mt < 2; ++mt)
#pragma unroll
    for (int r = 0; r < 4; ++r) {
      ssum[mt][r] = 0.f;
      pmax[mt][r] = 0.f;   // p > 0 always
      ai[mt][r] = 0;
    }

  __syncthreads();  // chunk 0 staged; n2s published

  // ---- main loop over 32 N-chunks of 32 columns ----
  for (int ch = 0; ch < 32; ++ch) {
    const unsigned short* buf = Bbuf[ch & 1];
    if (ch + 1 < 32) {
      const unsigned short* src = Cb + (size_t)(ch + 1) * 8192;
      unsigned short* dst = Bbuf[(ch + 1) & 1];
#pragma unroll
      for (int i = 0; i < 4; ++i) {
        int blk = i * 4 + wave;
        gld_lds16(src + blk * 512 + lane * 8, dst + blk * 512 + lane * 8);
      }
    }

    for (int nt = 0; nt < 2; ++nt) {
      f32x4 acc0 = {0.f, 0.f, 0.f, 0.f};
      f32x4 acc1 = {0.f, 0.f, 0.f, 0.f};
#pragma unroll
      for (int s = 0; s < 8; ++s) {
        short8 bfrag = *(const short8*)(buf + ((nt * 8 + s) * 64 + lane) * 8);
        acc0 = __builtin_amdgcn_mfma_f32_16x16x32_bf16(af[0][s], bfrag, acc0,
                                                       0, 0, 0);
        acc1 = __builtin_amdgcn_mfma_f32_16x16x32_bf16(af[1][s], bfrag, acc1,
                                                       0, 0, 0);
      }
      float dv[2][4];
#pragma unroll
      for (int r = 0; r < 4; ++r) { dv[0][r] = acc0[r]; dv[1][r] = acc1[r]; }

      // diagonal fixup — wave-uniform guard, only 1 of 64 nt-steps enters
      if ((jspk >> 4) == ch * 2 + nt) {
        if (c == (jspk & 15)) {
#pragma unroll
          for (int mt = 0; mt < 2; ++mt)
#pragma unroll
            for (int r = 0; r < 4; ++r) {
              int rl = wave * 32 + mt * 16 + q * 4 + r;
              float d = dv[mt][r];
              float n2 = n2s[rl];
              float Sv = d * ns;
              float den = fmaxf(fmaf(ns, ns, n2) - 2.f * Sv, 1e-30f);
              float val = (Sv - n2) * __frsqrt_rn(den);
              gtl[rl] = fmaf(w, val, bia);
              dv[mt][r] = val;
            }
        }
      }

      int col = ch * 32 + nt * 16 + c;
#pragma unroll
      for (int mt = 0; mt < 2; ++mt)
#pragma unroll
        for (int r = 0; r < 4; ++r) {
          float p = exp2f(fmaf(dv[mt][r], wl, cl));  // exp(l - M0), monotone
          ssum[mt][r] += p;
          if (p > pmax[mt][r]) {
            pmax[mt][r] = p;
            ai[mt][r] = col;
          }
        }
    }
    __syncthreads();
  }

  // ---- cross-lane (16 column-lanes) reduction per row-slot ----
#pragma unroll
  for (int mt = 0; mt < 2; ++mt)
#pragma unroll
    for (int r = 0; r < 4; ++r) {
      float s = ssum[mt][r];
      s += __shfl_xor(s, 1, 64);
      s += __shfl_xor(s, 2, 64);
      s += __shfl_xor(s, 4, 64);
      s += __shfl_xor(s, 8, 64);
      float m = pmax[mt][r];
      int idx = ai[mt][r];
#pragma unroll
      for (int off = 1; off < 16; off <<= 1) {
        float m2 = __shfl_xor(m, off, 64);
        int i2 = __shfl_xor(idx, off, 64);
        if (m2 > m || (m2 == m && i2 < idx)) { m = m2; idx = i2; }
      }
      if (c == 0) {
        int rl = wave * 32 + mt * 16 + q * 4 + r;
        sE[rl] = s;
        aE[rl] = idx;
      }
    }
  __syncthreads();

  // ---- final per-row combine (128 rows on waves 0,1) ----
  if (t < 128) {
    int spk = b0 * 2 + (t >> 6);  // wave-uniform
    float lse = M0 + __logf(sE[t]);
    float lossr = lse - gtl[t];
    float corr = (aE[t] == spk) ? 1.f : 0.f;
#pragma unroll
    for (int off = 32; off; off >>= 1) {
      lossr += __shfl_xor(lossr, off, 64);
      corr += __shfl_xor(corr, off, 64);
    }
    if ((t & 63) == 0) {
      const float inv = 1.f / (float)(NS * NU);
      atomicAdd(&out[0], lossr * inv);
      atomicAdd(&out[1], corr * inv);
    }
  }
}

extern "C" void kernel_launch(void* const* d_in, const int* in_sizes, int n_in,
                              void* d_out, int out_size, void* d_ws,
                              size_t ws_size, hipStream_t stream) {
  const float* embeds = (const float*)d_in[0];
  const float* w = (const float*)d_in[1];
  const float* b = (const float*)d_in[2];
  float* out = (float*)d_out;
  unsigned short* Cb = (unsigned short*)d_ws;   // 1024*256 bf16
  float* normsum = (float*)(Cb + NS * NE);      // 1024 floats

  centroid_kernel<<<NS, 256, 0, stream>>>(embeds, Cb, normsum, out);
  main_kernel<<<NS * NU / 128, 256, 0, stream>>>(embeds, Cb, normsum, w, b,
                                                 out);
}

// Round 5
// 174.127 us; speedup vs baseline: 1.2751x; 1.1270x over previous
//
#include <hip/hip_runtime.h>
#include <math.h>

#define NS 1024   // speakers
#define NU 64     // utterances per speaker
#define NE 256    // embedding dim

typedef __attribute__((ext_vector_type(8))) short short8;
typedef __attribute__((ext_vector_type(4))) float f32x4;
typedef __attribute__((ext_vector_type(4))) unsigned short us4;

// round-to-nearest-even fp32 -> bf16 bits
__device__ static inline unsigned short f2bf(float f) {
  unsigned int u = __float_as_uint(f);
  unsigned int r = (u + 0x7fffu + ((u >> 16) & 1u)) >> 16;
  return (unsigned short)r;
}

__device__ static inline void gld_lds16(const void* g, void* l) {
  __builtin_amdgcn_global_load_lds(
      (const __attribute__((address_space(1))) unsigned int*)g,
      (__attribute__((address_space(3))) unsigned int*)l, 16, 0, 0);
}

// Cb layout (bf16, MFMA-B-fragment-permuted):
// global 1KB block G = (n>>4)*8 + (k>>5); within block,
//   idx(n,k) = G*512 + (((k>>3)&3)*16 + (n&15))*8 + (k&7)   (ushort units)
// Chunk ch (32 cols) = blocks [ch*16, ch*16+16) -> contiguous 16 KB.

__global__ __launch_bounds__(256) void centroid_kernel(
    const float* __restrict__ embeds, unsigned short* __restrict__ Cb,
    float* __restrict__ normsum, float* __restrict__ out) {
  int k = blockIdx.x;   // speaker
  int t = threadIdx.x;
  int wave = t >> 6, e4 = t & 63;  // e4: float4 group (4 consecutive elems)
  const float4* base =
      (const float4*)(embeds + (size_t)k * NU * NE) + wave * 16 * 64 + e4;
  float4 s = {0.f, 0.f, 0.f, 0.f};
#pragma unroll
  for (int i = 0; i < 16; ++i) {
    float4 v = base[i * 64];
    s.x += v.x; s.y += v.y; s.z += v.z; s.w += v.w;
  }
  __shared__ float4 ps[4][64];
  ps[wave][e4] = s;
  __syncthreads();
  if (t < 64) {
    float4 a = ps[0][t], b = ps[1][t], c = ps[2][t], d = ps[3][t];
    float4 s4;
    s4.x = a.x + b.x + c.x + d.x;
    s4.y = a.y + b.y + c.y + d.y;
    s4.z = a.z + b.z + c.z + d.z;
    s4.w = a.w + b.w + c.w + d.w;
    float sq = s4.x * s4.x + s4.y * s4.y + s4.z * s4.z + s4.w * s4.w;
#pragma unroll
    for (int off = 32; off; off >>= 1) sq += __shfl_xor(sq, off, 64);
    float nrm = sqrtf(sq);
    float inv = 1.f / nrm;
    int G = (k >> 4) * 8 + (t >> 3);
    int off = (((t >> 1) & 3) * 16 + (k & 15)) * 8 + (t & 1) * 4;
    us4 v;
    v[0] = f2bf(s4.x * inv);
    v[1] = f2bf(s4.y * inv);
    v[2] = f2bf(s4.z * inv);
    v[3] = f2bf(s4.w * inv);
    *(us4*)(Cb + (size_t)G * 512 + off) = v;
    if (t == 0) {
      normsum[k] = nrm;
      if (k == 0) { out[0] = 0.f; out[1] = 0.f; }
    }
  }
}

__global__ __launch_bounds__(256, 3) void main_kernel(
    const float* __restrict__ embeds, const unsigned short* __restrict__ Cb,
    const float* __restrict__ normsum, const float* __restrict__ wp,
    const float* __restrict__ bp, float* __restrict__ out) {
  __shared__ __align__(16) unsigned short Bbuf[2][8192];  // 2 x 16 KB
  __shared__ float n2s[128];
  __shared__ float gtl[128];
  __shared__ float sE[128];
  __shared__ int aE[128];

  int t = threadIdx.x;
  int wave = t >> 6, lane = t & 63;
  int c = lane & 15, q = lane >> 4;
  int b0 = blockIdx.x;              // 0..511
  int jspk = b0 * 2 + (wave >> 1);  // this wave's speaker (diag column)
  int r0 = b0 * 128 + wave * 32;    // global row base for this wave

  float w = *wp, bia = *bp;
  const float L2E = 1.4426950408889634f;
  float M0 = fabsf(w) + bia;        // >= any logit (cosines in [-1,1])
  float wl = w * L2E;               // p = 2^(d*wl + cl) = exp(l - M0)
  float cl = (bia - M0) * L2E;
  float ns = normsum[jspk];

  // ---- issue chunk-0 staging first so L2 fetch overlaps A-load ----
  {
#pragma unroll
    for (int i = 0; i < 4; ++i) {
      int blk = i * 4 + wave;
      gld_lds16(Cb + blk * 512 + lane * 8, &Bbuf[0][blk * 512 + lane * 8]);
    }
  }

  // ---- load A fragments (32 rows x 256 K per wave) into registers ----
  // A-frag layout: lane holds A[m = lane&15][k = q*8 + j], per (mtile, kstep)
  short8 af[2][8];
  float n2p[2];
#pragma unroll
  for (int mt = 0; mt < 2; ++mt) {
    const float* rowp = embeds + (size_t)(r0 + mt * 16 + c) * NE;
    float acc2 = 0.f;
#pragma unroll
    for (int s = 0; s < 8; ++s) {
      int k0 = s * 32 + q * 8;
      float4 x = *(const float4*)(rowp + k0);
      float4 y = *(const float4*)(rowp + k0 + 4);
      acc2 += x.x * x.x + x.y * x.y + x.z * x.z + x.w * x.w;
      acc2 += y.x * y.x + y.y * y.y + y.z * y.z + y.w * y.w;
      short8 f;
      f[0] = (short)f2bf(x.x); f[1] = (short)f2bf(x.y);
      f[2] = (short)f2bf(x.z); f[3] = (short)f2bf(x.w);
      f[4] = (short)f2bf(y.x); f[5] = (short)f2bf(y.y);
      f[6] = (short)f2bf(y.z); f[7] = (short)f2bf(y.w);
      af[mt][s] = f;
    }
    n2p[mt] = acc2;
  }
#pragma unroll
  for (int mt = 0; mt < 2; ++mt) {
    n2p[mt] += __shfl_xor(n2p[mt], 16, 64);
    n2p[mt] += __shfl_xor(n2p[mt], 32, 64);
  }
  if (q == 0) {
    n2s[wave * 32 + c] = n2p[0];
    n2s[wave * 32 + 16 + c] = n2p[1];
  }

  // ---- per-lane softmax state (2 mtiles x 4 regs = 8 row-slots) ----
  float ssum[2][4];
  float pmax[2][4];
  int ai[2][4];
#pragma unroll
  for (int mt = 0; mt < 2; ++mt)
#pragma unroll
    for (int r = 0; r < 4; ++r) {
      ssum[mt][r] = 0.f;
      pmax[mt][r] = 0.f;   // p > 0 always
      ai[mt][r] = 0;
    }

  __syncthreads();  // chunk 0 staged; n2s published

  // ---- main loop over 32 N-chunks of 32 columns ----
  for (int ch = 0; ch < 32; ++ch) {
    const unsigned short* buf = Bbuf[ch & 1];
    if (ch + 1 < 32) {
      const unsigned short* src = Cb + (size_t)(ch + 1) * 8192;
      unsigned short* dst = Bbuf[(ch + 1) & 1];
#pragma unroll
      for (int i = 0; i < 4; ++i) {
        int blk = i * 4 + wave;
        gld_lds16(src + blk * 512 + lane * 8, dst + blk * 512 + lane * 8);
      }
    }

    for (int nt = 0; nt < 2; ++nt) {
      f32x4 acc0 = {0.f, 0.f, 0.f, 0.f};
      f32x4 acc1 = {0.f, 0.f, 0.f, 0.f};
#pragma unroll
      for (int s = 0; s < 8; ++s) {
        short8 bfrag = *(const short8*)(buf + ((nt * 8 + s) * 64 + lane) * 8);
        acc0 = __builtin_amdgcn_mfma_f32_16x16x32_bf16(af[0][s], bfrag, acc0,
                                                       0, 0, 0);
        acc1 = __builtin_amdgcn_mfma_f32_16x16x32_bf16(af[1][s], bfrag, acc1,
                                                       0, 0, 0);
      }

      bool diagstep = ((jspk >> 4) == ch * 2 + nt);  // wave-uniform
      int col = ch * 32 + nt * 16 + c;
#pragma unroll
      for (int mt = 0; mt < 2; ++mt) {
        f32x4 a = mt ? acc1 : acc0;
        if (diagstep && c == (jspk & 15)) {
#pragma unroll
          for (int r = 0; r < 4; ++r) {
            int rl = wave * 32 + mt * 16 + q * 4 + r;
            float d = a[r];
            float n2 = n2s[rl];
            float Sv = d * ns;
            float den = fmaxf(fmaf(ns, ns, n2) - 2.f * Sv, 1e-30f);
            float val = (Sv - n2) * __frsqrt_rn(den);
            gtl[rl] = fmaf(w, val, bia);
            a[r] = val;
          }
        }
#pragma unroll
        for (int r = 0; r < 4; ++r) {
          float p = exp2f(fmaf(a[r], wl, cl));  // exp(l - M0), monotone in l
          ssum[mt][r] += p;
          if (p > pmax[mt][r]) {
            pmax[mt][r] = p;
            ai[mt][r] = col;
          }
        }
      }
    }
    __syncthreads();
  }

  // ---- cross-lane (16 column-lanes) reduction per row-slot ----
#pragma unroll
  for (int mt = 0; mt < 2; ++mt)
#pragma unroll
    for (int r = 0; r < 4; ++r) {
      float s = ssum[mt][r];
      s += __shfl_xor(s, 1, 64);
      s += __shfl_xor(s, 2, 64);
      s += __shfl_xor(s, 4, 64);
      s += __shfl_xor(s, 8, 64);
      float m = pmax[mt][r];
      int idx = ai[mt][r];
#pragma unroll
      for (int off = 1; off < 16; off <<= 1) {
        float m2 = __shfl_xor(m, off, 64);
        int i2 = __shfl_xor(idx, off, 64);
        if (m2 > m || (m2 == m && i2 < idx)) { m = m2; idx = i2; }
      }
      if (c == 0) {
        int rl = wave * 32 + mt * 16 + q * 4 + r;
        sE[rl] = s;
        aE[rl] = idx;
      }
    }
  __syncthreads();

  // ---- final per-row combine (128 rows on waves 0,1) ----
  if (t < 128) {
    int spk = b0 * 2 + (t >> 6);  // wave-uniform
    float lse = M0 + __logf(sE[t]);
    float lossr = lse - gtl[t];
    float corr = (aE[t] == spk) ? 1.f : 0.f;
#pragma unroll
    for (int off = 32; off; off >>= 1) {
      lossr += __shfl_xor(lossr, off, 64);
      corr += __shfl_xor(corr, off, 64);
    }
    if ((t & 63) == 0) {
      const float inv = 1.f / (float)(NS * NU);
      atomicAdd(&out[0], lossr * inv);
      atomicAdd(&out[1], corr * inv);
    }
  }
}

extern "C" void kernel_launch(void* const* d_in, const int* in_sizes, int n_in,
                              void* d_out, int out_size, void* d_ws,
                              size_t ws_size, hipStream_t stream) {
  const float* embeds = (const float*)d_in[0];
  const float* w = (const float*)d_in[1];
  const float* b = (const float*)d_in[2];
  float* out = (float*)d_out;
  unsigned short* Cb = (unsigned short*)d_ws;   // 1024*256 bf16
  float* normsum = (float*)(Cb + NS * NE);      // 1024 floats

  centroid_kernel<<<NS, 256, 0, stream>>>(embeds, Cb, normsum, out);
  main_kernel<<<NS * NU / 128, 256, 0, stream>>>(embeds, Cb, normsum, w, b,
                                                 out);
}

// Round 6
// 168.528 us; speedup vs baseline: 1.3175x; 1.0332x over previous
//
#include <hip/hip_runtime.h>
#include <math.h>

#define NS 1024   // speakers
#define NU 64     // utterances per speaker
#define NE 256    // embedding dim

typedef __attribute__((ext_vector_type(8))) short short8;
typedef __attribute__((ext_vector_type(4))) float f32x4;
typedef __attribute__((ext_vector_type(4))) unsigned short us4;

// round-to-nearest-even fp32 -> bf16 bits
__device__ static inline unsigned short f2bf(float f) {
  unsigned int u = __float_as_uint(f);
  unsigned int r = (u + 0x7fffu + ((u >> 16) & 1u)) >> 16;
  return (unsigned short)r;
}

__device__ static inline void gld_lds16(const void* g, void* l) {
  __builtin_amdgcn_global_load_lds(
      (const __attribute__((address_space(1))) unsigned int*)g,
      (__attribute__((address_space(3))) unsigned int*)l, 16, 0, 0);
}

// ws layout (bytes):
//   Cb    @ 0        : 1024*256 bf16 (512 KB), MFMA-B-permuted
//   packG @ 512K     : 65536 u64  (512 KB)  argmax packed (p_bits<<32 | 1023-col)
//   ssumG @ 1024K    : 65536 f32  (256 KB)  sum of exp(l-M0) per row
//   gtlG  @ 1280K    : 65536 f32  (256 KB)  ground-truth logit per row
//   normsum @ 1536K  : 1024 f32
//
// Cb layout: global 1KB block G = (n>>4)*8 + (k>>5); within block,
//   idx(n,k) = G*512 + (((k>>3)&3)*16 + (n&15))*8 + (k&7)   (ushort units)
// Chunk ch (32 cols) = 8192 consecutive ushorts (16 KB).

__global__ __launch_bounds__(256) void centroid_kernel(
    const float* __restrict__ embeds, unsigned short* __restrict__ Cb,
    float* __restrict__ normsum, float* __restrict__ ssumG,
    unsigned long long* __restrict__ packG, float* __restrict__ out) {
  int k = blockIdx.x;   // speaker
  int t = threadIdx.x;
  // zero the per-row accumulators (re-poisoned to 0xAA every launch)
  if (t < 64) {
    ssumG[k * 64 + t] = 0.f;
    packG[k * 64 + t] = 0ull;
  }
  int wave = t >> 6, e4 = t & 63;
  const float4* base =
      (const float4*)(embeds + (size_t)k * NU * NE) + wave * 16 * 64 + e4;
  float4 s = {0.f, 0.f, 0.f, 0.f};
#pragma unroll
  for (int i = 0; i < 16; ++i) {
    float4 v = base[i * 64];
    s.x += v.x; s.y += v.y; s.z += v.z; s.w += v.w;
  }
  __shared__ float4 ps[4][64];
  ps[wave][e4] = s;
  __syncthreads();
  if (t < 64) {
    float4 a = ps[0][t], b = ps[1][t], c = ps[2][t], d = ps[3][t];
    float4 s4;
    s4.x = a.x + b.x + c.x + d.x;
    s4.y = a.y + b.y + c.y + d.y;
    s4.z = a.z + b.z + c.z + d.z;
    s4.w = a.w + b.w + c.w + d.w;
    float sq = s4.x * s4.x + s4.y * s4.y + s4.z * s4.z + s4.w * s4.w;
#pragma unroll
    for (int off = 32; off; off >>= 1) sq += __shfl_xor(sq, off, 64);
    float nrm = sqrtf(sq);
    float inv = 1.f / nrm;
    int G = (k >> 4) * 8 + (t >> 3);
    int off = (((t >> 1) & 3) * 16 + (k & 15)) * 8 + (t & 1) * 4;
    us4 v;
    v[0] = f2bf(s4.x * inv);
    v[1] = f2bf(s4.y * inv);
    v[2] = f2bf(s4.z * inv);
    v[3] = f2bf(s4.w * inv);
    *(us4*)(Cb + (size_t)G * 512 + off) = v;
    if (t == 0) {
      normsum[k] = nrm;
      if (k == 0) { out[0] = 0.f; out[1] = 0.f; }
    }
  }
}

__global__ __launch_bounds__(256, 3) void main_kernel(
    const float* __restrict__ embeds, const unsigned short* __restrict__ Cb,
    const float* __restrict__ normsum, const float* __restrict__ wp,
    const float* __restrict__ bp, float* __restrict__ ssumG,
    unsigned long long* __restrict__ packG, float* __restrict__ gtlG) {
  __shared__ __align__(16) unsigned short Bbuf[2][8192];  // 2 x 16 KB
  __shared__ float n2s[128];

  int t = threadIdx.x;
  int wave = t >> 6, lane = t & 63;
  int c = lane & 15, q = lane >> 4;
  int b = blockIdx.x;               // 0..1023
  int rg = b >> 1;                  // row group 0..511
  int h = b & 1;                    // column half: cols [h*512, h*512+512)
  int jspk = rg * 2 + (wave >> 1);  // this wave's speaker (diag column)
  int r0 = rg * 128 + wave * 32;    // global row base for this wave

  float w = *wp, bia = *bp;
  const float L2E = 1.4426950408889634f;
  float M0 = fabsf(w) + bia;        // >= any logit (cosines in [-1,1])
  float wl = w * L2E;               // p = 2^(d*wl + cl) = exp(l - M0)
  float cl = (bia - M0) * L2E;
  float ns = normsum[jspk];

  // ---- issue first-chunk staging so L2 fetch overlaps A-load ----
  {
    const unsigned short* src = Cb + (size_t)h * 16 * 8192;
#pragma unroll
    for (int i = 0; i < 4; ++i) {
      int blk = i * 4 + wave;
      gld_lds16(src + blk * 512 + lane * 8, &Bbuf[0][blk * 512 + lane * 8]);
    }
  }

  // ---- load A fragments (32 rows x 256 K per wave) into registers ----
  // A-frag layout: lane holds A[m = lane&15][k = q*8 + j], per (mtile, kstep)
  short8 af[2][8];
  float n2p[2];
#pragma unroll
  for (int mt = 0; mt < 2; ++mt) {
    const float* rowp = embeds + (size_t)(r0 + mt * 16 + c) * NE;
    float acc2 = 0.f;
#pragma unroll
    for (int s = 0; s < 8; ++s) {
      int k0 = s * 32 + q * 8;
      float4 x = *(const float4*)(rowp + k0);
      float4 y = *(const float4*)(rowp + k0 + 4);
      acc2 += x.x * x.x + x.y * x.y + x.z * x.z + x.w * x.w;
      acc2 += y.x * y.x + y.y * y.y + y.z * y.z + y.w * y.w;
      short8 f;
      f[0] = (short)f2bf(x.x); f[1] = (short)f2bf(x.y);
      f[2] = (short)f2bf(x.z); f[3] = (short)f2bf(x.w);
      f[4] = (short)f2bf(y.x); f[5] = (short)f2bf(y.y);
      f[6] = (short)f2bf(y.z); f[7] = (short)f2bf(y.w);
      af[mt][s] = f;
    }
    n2p[mt] = acc2;
  }
#pragma unroll
  for (int mt = 0; mt < 2; ++mt) {
    n2p[mt] += __shfl_xor(n2p[mt], 16, 64);
    n2p[mt] += __shfl_xor(n2p[mt], 32, 64);
  }
  if (q == 0) {
    n2s[wave * 32 + c] = n2p[0];
    n2s[wave * 32 + 16 + c] = n2p[1];
  }

  // ---- per-lane softmax state (2 mtiles x 4 regs = 8 row-slots) ----
  float ssum[2][4];
  float pmax[2][4];
  int ai[2][4];
#pragma unroll
  for (int mt = 0; mt < 2; ++mt)
#pragma unroll
    for (int r = 0; r < 4; ++r) {
      ssum[mt][r] = 0.f;
      pmax[mt][r] = 0.f;   // p > 0 always
      ai[mt][r] = 0;
    }

  __syncthreads();  // chunk 0 staged; n2s published

  // ---- loop over this half's 16 N-chunks of 32 columns ----
  for (int cc = 0; cc < 16; ++cc) {
    int gc = h * 16 + cc;  // global chunk
    const unsigned short* buf = Bbuf[cc & 1];
    if (cc + 1 < 16) {
      const unsigned short* src = Cb + (size_t)(gc + 1) * 8192;
      unsigned short* dst = Bbuf[(cc + 1) & 1];
#pragma unroll
      for (int i = 0; i < 4; ++i) {
        int blk = i * 4 + wave;
        gld_lds16(src + blk * 512 + lane * 8, dst + blk * 512 + lane * 8);
      }
    }

    for (int nt = 0; nt < 2; ++nt) {
      f32x4 acc0 = {0.f, 0.f, 0.f, 0.f};
      f32x4 acc1 = {0.f, 0.f, 0.f, 0.f};
#pragma unroll
      for (int s = 0; s < 8; ++s) {
        short8 bfrag = *(const short8*)(buf + ((nt * 8 + s) * 64 + lane) * 8);
        acc0 = __builtin_amdgcn_mfma_f32_16x16x32_bf16(af[0][s], bfrag, acc0,
                                                       0, 0, 0);
        acc1 = __builtin_amdgcn_mfma_f32_16x16x32_bf16(af[1][s], bfrag, acc1,
                                                       0, 0, 0);
      }

      bool diagstep = ((jspk >> 4) == gc * 2 + nt);  // wave-uniform
      int col = gc * 32 + nt * 16 + c;
#pragma unroll
      for (int mt = 0; mt < 2; ++mt) {
        f32x4 a = mt ? acc1 : acc0;
        if (diagstep && c == (jspk & 15)) {
#pragma unroll
          for (int r = 0; r < 4; ++r) {
            int rl = wave * 32 + mt * 16 + q * 4 + r;
            float d = a[r];
            float n2 = n2s[rl];
            float Sv = d * ns;
            float den = fmaxf(fmaf(ns, ns, n2) - 2.f * Sv, 1e-30f);
            float val = (Sv - n2) * __frsqrt_rn(den);
            gtlG[r0 + mt * 16 + q * 4 + r] = fmaf(w, val, bia);
            a[r] = val;
          }
        }
#pragma unroll
        for (int r = 0; r < 4; ++r) {
          float p = exp2f(fmaf(a[r], wl, cl));  // exp(l - M0), monotone in l
          ssum[mt][r] += p;
          if (p > pmax[mt][r]) {
            pmax[mt][r] = p;
            ai[mt][r] = col;
          }
        }
      }
    }
    __syncthreads();
  }

  // ---- cross-lane (16 column-lanes) reduce, then global atomic combine ----
#pragma unroll
  for (int mt = 0; mt < 2; ++mt)
#pragma unroll
    for (int r = 0; r < 4; ++r) {
      float s = ssum[mt][r];
      s += __shfl_xor(s, 1, 64);
      s += __shfl_xor(s, 2, 64);
      s += __shfl_xor(s, 4, 64);
      s += __shfl_xor(s, 8, 64);
      float m = pmax[mt][r];
      int idx = ai[mt][r];
#pragma unroll
      for (int off = 1; off < 16; off <<= 1) {
        float m2 = __shfl_xor(m, off, 64);
        int i2 = __shfl_xor(idx, off, 64);
        if (m2 > m || (m2 == m && i2 < idx)) { m = m2; idx = i2; }
      }
      if (c == 0) {
        int row = r0 + mt * 16 + q * 4 + r;
        atomicAdd(&ssumG[row], s);
        // pack: p bits in high 32 (p>0 so bits monotone), 1023-col low
        // (ties resolve to LOWEST col, matching jnp.argmax)
        unsigned long long pk =
            ((unsigned long long)__float_as_uint(m) << 32) |
            (unsigned long long)(unsigned)(1023 - idx);
        atomicMax(&packG[row], pk);
      }
    }
}

__global__ __launch_bounds__(256) void reduce_kernel(
    const float* __restrict__ ssumG, const unsigned long long* __restrict__ packG,
    const float* __restrict__ gtlG, const float* __restrict__ wp,
    const float* __restrict__ bp, float* __restrict__ out) {
  int i = blockIdx.x * 256 + threadIdx.x;  // row 0..65535
  int spk = i >> 6;
  float w = *wp, bia = *bp;
  float M0 = fabsf(w) + bia;
  float lossr = M0 + __logf(ssumG[i]) - gtlG[i];
  int amax = 1023 - (int)(unsigned)(packG[i] & 0xffffffffull);
  float corr = (amax == spk) ? 1.f : 0.f;
#pragma unroll
  for (int off = 32; off; off >>= 1) {
    lossr += __shfl_xor(lossr, off, 64);
    corr += __shfl_xor(corr, off, 64);
  }
  __shared__ float pl[4], pc[4];
  int wave = threadIdx.x >> 6, lane = threadIdx.x & 63;
  if (lane == 0) { pl[wave] = lossr; pc[wave] = corr; }
  __syncthreads();
  if (threadIdx.x == 0) {
    const float inv = 1.f / (float)(NS * NU);
    atomicAdd(&out[0], (pl[0] + pl[1] + pl[2] + pl[3]) * inv);
    atomicAdd(&out[1], (pc[0] + pc[1] + pc[2] + pc[3]) * inv);
  }
}

extern "C" void kernel_launch(void* const* d_in, const int* in_sizes, int n_in,
                              void* d_out, int out_size, void* d_ws,
                              size_t ws_size, hipStream_t stream) {
  const float* embeds = (const float*)d_in[0];
  const float* w = (const float*)d_in[1];
  const float* b = (const float*)d_in[2];
  float* out = (float*)d_out;
  char* ws = (char*)d_ws;
  unsigned short* Cb = (unsigned short*)ws;                       // 512 KB
  unsigned long long* packG = (unsigned long long*)(ws + (512 << 10));  // 512 KB
  float* ssumG = (float*)(ws + (1024 << 10));                     // 256 KB
  float* gtlG = (float*)(ws + (1280 << 10));                      // 256 KB
  float* normsum = (float*)(ws + (1536 << 10));                   // 4 KB

  centroid_kernel<<<NS, 256, 0, stream>>>(embeds, Cb, normsum, ssumG, packG,
                                          out);
  main_kernel<<<1024, 256, 0, stream>>>(embeds, Cb, normsum, w, b, ssumG,
                                        packG, gtlG);
  reduce_kernel<<<NS * NU / 256, 256, 0, stream>>>(ssumG, packG, gtlG, w, b,
                                                   out);
}